// Round 15
// baseline (254.033 us; speedup 1.0000x reference)
//
#include <hip/hip_runtime.h>
#include <hip/hip_bf16.h>

#define NEG_SLOPE 0.2f

typedef short bf16x8 __attribute__((ext_vector_type(8)));
typedef float f32x4 __attribute__((ext_vector_type(4)));

__device__ __forceinline__ unsigned short f2bf(float f) {
    unsigned int u = __float_as_uint(f);
    unsigned int r = (u + 0x7fffu + ((u >> 16) & 1u)) >> 16;
    return (unsigned short)r;
}
__device__ __forceinline__ float bf2f(unsigned short h) {
    return __uint_as_float(((unsigned int)h) << 16);
}

// ---------------------------------------------------------------------------
// K0: prep. Wt_fc[144][128] = [W_fc^T ; (W_fc@attn_l)^T ; (W_fc@attn_r)^T].
// Wt_cb[128][256] = theta*W_comb^T + c1*I(k==c) + c2*I(k==c+128).
// bvec[128] = theta*(gat_bias @ W_comb_top) + c1*gat_bias.
// ---------------------------------------------------------------------------
__global__ __launch_bounds__(256) void prep_kernel(
    const float* __restrict__ W_fc, const float* __restrict__ attn_l,
    const float* __restrict__ attn_r, const float* __restrict__ W_comb,
    const float* __restrict__ gat_bias,
    const int* __restrict__ l_p, const float* __restrict__ lamda_p,
    const float* __restrict__ alpha_p,
    unsigned short* __restrict__ Wt_fc, unsigned short* __restrict__ Wt_cb,
    float* __restrict__ bvec)
{
    const float alpha = alpha_p[0];
    const float theta = fminf(1.0f, logf(lamda_p[0] / (float)l_p[0] + 1.0f));
    const float c1 = (1.f - theta) * (1.f - alpha);
    const float c2 = (1.f - theta) * alpha;

    const int t = blockIdx.x * 256 + threadIdx.x;
    const int stride = gridDim.x * 256;
    for (int i = t; i < 128 * 128; i += stride) {
        const int c = i >> 7, k = i & 127;
        Wt_fc[c * 128 + k] = f2bf(W_fc[k * 128 + c]);
    }
    for (int i = t; i < 8 * 128; i += stride) {
        const int hd = i >> 7, k = i & 127;
        float sl = 0.f, sr = 0.f;
        for (int d = 0; d < 16; ++d) {
            const float w = W_fc[k * 128 + hd * 16 + d];
            sl += w * attn_l[hd * 16 + d];
            sr += w * attn_r[hd * 16 + d];
        }
        Wt_fc[(128 + hd) * 128 + k] = f2bf(sl);
        Wt_fc[(136 + hd) * 128 + k] = f2bf(sr);
    }
    for (int i = t; i < 128 * 256; i += stride) {
        const int c = i >> 8, k = i & 255;
        float w = theta * W_comb[k * 128 + c];
        if (k == c) w += c1;
        if (k == c + 128) w += c2;
        Wt_cb[c * 256 + k] = f2bf(w);
    }
    for (int c = t; c < 128; c += stride) {
        float s = c1 * gat_bias[c];
        for (int k = 0; k < 128; ++k)
            s += theta * gat_bias[k] * W_comb[k * 128 + c];
        bvec[c] = s;
    }
}

// ---------------------------------------------------------------------------
// K1: h = input @ W_fc via bf16 MFMA, el/er as output cols 128..143.
// A-fragments (4 chunks) in registers. ONE-SHOT B staging: all of Wt_fc
// (39 KB incl. pad) into LDS, single barrier, then 36 ds_read+MFMA pairs
// with no further sync. Pad 136 (68-dword stride): fragment rows spread
// evenly over all 32 banks.
// ---------------------------------------------------------------------------
__global__ __launch_bounds__(256) void fc_gemm_kernel(
    const float* __restrict__ A, const unsigned short* __restrict__ Wt,
    unsigned short* __restrict__ h, float* __restrict__ el,
    float* __restrict__ er, int n)
{
    __shared__ unsigned short Bs[144][136];
    const int tid = threadIdx.x;
    const int wave = tid >> 6;
    const int lane = tid & 63;
    const int m16 = lane & 15;
    const int kg = lane >> 4;
    const int rowBase = blockIdx.x * 64;

    // A in registers: all 4 chunks, issued first (HBM latency covered by
    // the B staging + barrier below).
    int arow = rowBase + wave * 16 + m16;
    if (arow >= n) arow = n - 1;
    const long long aoff = (long long)arow * 128;
    bf16x8 af[4];
#pragma unroll
    for (int ci = 0; ci < 4; ++ci) {
        const float4 v0 = *(const float4*)&A[aoff + ci * 32 + kg * 8];
        const float4 v1 = *(const float4*)&A[aoff + ci * 32 + kg * 8 + 4];
        bf16x8 pk;
        pk[0] = (short)f2bf(v0.x); pk[1] = (short)f2bf(v0.y);
        pk[2] = (short)f2bf(v0.z); pk[3] = (short)f2bf(v0.w);
        pk[4] = (short)f2bf(v1.x); pk[5] = (short)f2bf(v1.y);
        pk[6] = (short)f2bf(v1.z); pk[7] = (short)f2bf(v1.w);
        af[ci] = pk;
    }

    // one-shot B staging: 144 rows x 16 bf16x8 units = 2304 units, 9/thread
#pragma unroll
    for (int u = tid; u < 2304; u += 256) {
        const int r = u >> 4, p = u & 15;
        *(bf16x8*)&Bs[r][p * 8] = *(const bf16x8*)&Wt[r * 128 + p * 8];
    }
    __syncthreads();

    f32x4 acc[9];
#pragma unroll
    for (int t = 0; t < 9; ++t) acc[t] = (f32x4){0.f, 0.f, 0.f, 0.f};

#pragma unroll
    for (int ci = 0; ci < 4; ++ci) {
#pragma unroll
        for (int t = 0; t < 9; ++t) {
            const bf16x8 bfrag = *(const bf16x8*)&Bs[t * 16 + m16][ci * 32 + kg * 8];
            acc[t] = __builtin_amdgcn_mfma_f32_16x16x32_bf16(af[ci], bfrag, acc[t], 0, 0, 0);
        }
    }

    const int r0 = rowBase + wave * 16 + kg * 4;
#pragma unroll
    for (int t = 0; t < 8; ++t) {
#pragma unroll
        for (int j = 0; j < 4; ++j) {
            const int row = r0 + j;
            if (row < n)
                h[(long long)row * 128 + t * 16 + m16] = f2bf(acc[t][j]);
        }
    }
#pragma unroll
    for (int j = 0; j < 4; ++j) {
        const int row = r0 + j;
        if (row < n) {
            const float v = acc[8][j];
            if (m16 < 8) el[(long long)row * 8 + m16] = v;
            else         er[(long long)row * 8 + (m16 - 8)] = v;
        }
    }
}

// ---------------------------------------------------------------------------
// CSR build: histogram -> 2-level exclusive scan -> scatter src ids by dst.
// ---------------------------------------------------------------------------
__global__ __launch_bounds__(256) void hist_kernel(
    const int* __restrict__ dst, int* __restrict__ deg, int E)
{
    const int i = blockIdx.x * 256 + threadIdx.x;
    if (i < E) atomicAdd(&deg[dst[i]], 1);
}

__global__ __launch_bounds__(256) void scan1_kernel(
    const int* __restrict__ deg, int* __restrict__ row,
    int* __restrict__ blockSums, int n)
{
    __shared__ int sdata[256];
    const int t = threadIdx.x;
    const int base = blockIdx.x * 1024 + t * 4;
    int v[4];
    int tot = 0;
#pragma unroll
    for (int j = 0; j < 4; ++j) {
        v[j] = (base + j < n) ? deg[base + j] : 0;
        tot += v[j];
    }
    sdata[t] = tot;
    __syncthreads();
    for (int off = 1; off < 256; off <<= 1) {
        const int x = (t >= off) ? sdata[t - off] : 0;
        __syncthreads();
        sdata[t] += x;
        __syncthreads();
    }
    if (t == 255) blockSums[blockIdx.x] = sdata[255];
    int run = sdata[t] - tot;
#pragma unroll
    for (int j = 0; j < 4; ++j) {
        if (base + j < n) row[base + j] = run;
        run += v[j];
    }
}

__global__ __launch_bounds__(128) void scan2_kernel(
    int* __restrict__ blockSums, int nb)
{
    __shared__ int sdata[128];
    const int t = threadIdx.x;
    const int v = (t < nb) ? blockSums[t] : 0;
    sdata[t] = v;
    __syncthreads();
    for (int off = 1; off < 128; off <<= 1) {
        const int x = (t >= off) ? sdata[t - off] : 0;
        __syncthreads();
        sdata[t] += x;
        __syncthreads();
    }
    if (t < nb) blockSums[t] = sdata[t] - v;
}

__global__ __launch_bounds__(256) void scan3_kernel(
    int* __restrict__ row, int* __restrict__ cursor,
    const int* __restrict__ blockSums, int n, int E)
{
    const int i = blockIdx.x * 256 + threadIdx.x;
    if (i == 0) row[n] = E;
    if (i >= n) return;
    const int r = row[i] + blockSums[i >> 10];
    row[i] = r;
    cursor[i] = r;
}

__global__ __launch_bounds__(256) void scatter_kernel(
    const int* __restrict__ src, const int* __restrict__ dst,
    int* __restrict__ cursor, int* __restrict__ srcs, int E)
{
    const int i = blockIdx.x * 256 + threadIdx.x;
    if (i >= E) return;
    const int pos = atomicAdd(&cursor[dst[i]], 1);
    srcs[pos] = src[i];
}

// ---------------------------------------------------------------------------
// K3: aggregate. One wave per dst node, ushort2/lane, one head per lane,
// cooperative srcs batch + shfl broadcast, x2 unroll. rst written bf16.
// ---------------------------------------------------------------------------
__global__ __launch_bounds__(256) void aggregate_kernel(
    const float* __restrict__ el, const float* __restrict__ er,
    const unsigned short* __restrict__ h, const int* __restrict__ row,
    const int* __restrict__ srcs, unsigned short* __restrict__ rst, int n)
{
    const int d = blockIdx.x * 4 + (threadIdx.x >> 6);
    const int lane = threadIdx.x & 63;
    if (d >= n) return;
    const int start = row[d], end = row[d + 1];
    const int hd = lane >> 3;
    const float erd = er[(long long)d * 8 + hd];

    float acc0 = 0.f, acc1 = 0.f, den = 0.f;
    for (int p = start; p < end; p += 64) {
        const int cnt = min(64, end - p);
        const int sv = srcs[p + (lane < cnt ? lane : cnt - 1)];
        int j = 0;
        for (; j + 1 < cnt; j += 2) {
            const int s0 = __shfl(sv, j);
            const int s1 = __shfl(sv, j + 1);
            const float g0 = el[(long long)s0 * 8 + hd];
            const float g1 = el[(long long)s1 * 8 + hd];
            const unsigned int u0 = *(const unsigned int*)&h[(long long)s0 * 128 + lane * 2];
            const unsigned int u1 = *(const unsigned int*)&h[(long long)s1 * 128 + lane * 2];
            float e0 = g0 + erd; e0 = e0 >= 0.f ? e0 : NEG_SLOPE * e0;
            float e1 = g1 + erd; e1 = e1 >= 0.f ? e1 : NEG_SLOPE * e1;
            const float w0 = __expf(e0);
            const float w1 = __expf(e1);
            den += w0 + w1;
            acc0 += w0 * __uint_as_float(u0 << 16)
                  + w1 * __uint_as_float(u1 << 16);
            acc1 += w0 * __uint_as_float(u0 & 0xffff0000u)
                  + w1 * __uint_as_float(u1 & 0xffff0000u);
        }
        if (j < cnt) {
            const int s0 = __shfl(sv, j);
            const unsigned int u0 = *(const unsigned int*)&h[(long long)s0 * 128 + lane * 2];
            float e0 = el[(long long)s0 * 8 + hd] + erd;
            e0 = e0 >= 0.f ? e0 : NEG_SLOPE * e0;
            const float w0 = __expf(e0);
            den += w0;
            acc0 += w0 * __uint_as_float(u0 << 16);
            acc1 += w0 * __uint_as_float(u0 & 0xffff0000u);
        }
    }
    ushort2 o;
    if (end > start) {
        const float inv = 1.f / den;
        o.x = f2bf(acc0 * inv);
        o.y = f2bf(acc1 * inv);
    } else {
        o.x = 0; o.y = 0;
    }
    *(ushort2*)&rst[(long long)d * 128 + lane * 2] = o;
}

// ---------------------------------------------------------------------------
// K4: GCNII combine via bf16 MFMA, fully folded: out = acc + bvec + input.
// A-fragments (8 chunks) in registers. ONE-SHOT B staging: all of Wt_cb
// (67.6 KB incl. pad, dynamic LDS) staged once, single barrier, then all
// 64 ds_read+MFMA pairs with no further sync. Fused GraphNorm stats.
// ---------------------------------------------------------------------------
__global__ __launch_bounds__(256) void combine_gemm_kernel(
    const unsigned short* __restrict__ rst, const float* __restrict__ h0,
    const float* __restrict__ input, const unsigned short* __restrict__ Wt,
    const float* __restrict__ bvec, const int* __restrict__ cums, int nb,
    float* __restrict__ sums, float* __restrict__ sumsq,
    float* __restrict__ x, int n)
{
    extern __shared__ char smem_dyn[];
    unsigned short (*Bs)[264] = (unsigned short(*)[264])smem_dyn;   // 128 rows
    float* s_sum = (float*)(smem_dyn + 128 * 264 * 2);
    float* s_sq  = s_sum + 128;

    const int tid = threadIdx.x;
    const int wave = tid >> 6;
    const int lane = tid & 63;
    const int m16 = lane & 15;
    const int kg = lane >> 4;
    const int rowBase = blockIdx.x * 64;

    if (tid < 128) { s_sum[tid] = 0.f; s_sq[tid] = 0.f; }

    // A in registers: 8 chunks (rst 0-3 direct bf16, h0 4-7 cvt), issued
    // first so their HBM latency hides under B staging + barrier.
    int arow = rowBase + wave * 16 + m16;
    if (arow >= n) arow = n - 1;
    const long long aoff = (long long)arow * 128;
    bf16x8 af[8];
#pragma unroll
    for (int ci = 0; ci < 4; ++ci)
        af[ci] = *(const bf16x8*)&rst[aoff + ci * 32 + kg * 8];
#pragma unroll
    for (int ci = 0; ci < 4; ++ci) {
        const float4 v0 = *(const float4*)&h0[aoff + ci * 32 + kg * 8];
        const float4 v1 = *(const float4*)&h0[aoff + ci * 32 + kg * 8 + 4];
        bf16x8 pk;
        pk[0] = (short)f2bf(v0.x); pk[1] = (short)f2bf(v0.y);
        pk[2] = (short)f2bf(v0.z); pk[3] = (short)f2bf(v0.w);
        pk[4] = (short)f2bf(v1.x); pk[5] = (short)f2bf(v1.y);
        pk[6] = (short)f2bf(v1.z); pk[7] = (short)f2bf(v1.w);
        af[4 + ci] = pk;
    }

    // one-shot B staging: 128 rows x 32 bf16x8 units = 4096 units, 16/thread
#pragma unroll
    for (int u = tid; u < 4096; u += 256) {
        const int r = u >> 5, p = u & 31;
        *(bf16x8*)&Bs[r][p * 8] = *(const bf16x8*)&Wt[r * 256 + p * 8];
    }
    __syncthreads();

    f32x4 acc[8];
#pragma unroll
    for (int t = 0; t < 8; ++t) acc[t] = (f32x4){0.f, 0.f, 0.f, 0.f};

#pragma unroll
    for (int ci = 0; ci < 8; ++ci) {
#pragma unroll
        for (int t = 0; t < 8; ++t) {
            const bf16x8 bfrag = *(const bf16x8*)&Bs[t * 16 + m16][ci * 32 + kg * 8];
            acc[t] = __builtin_amdgcn_mfma_f32_16x16x32_bf16(af[ci], bfrag, acc[t], 0, 0, 0);
        }
    }

    // ---- epilogue: out = acc + bvec + input, fused GraphNorm partials ----
    int lo = 0, hi = nb;
    while (hi - lo > 1) {
        const int mid = (lo + hi) >> 1;
        if (cums[mid] <= rowBase) lo = mid; else hi = mid;
    }
    const int sid0 = lo;
    const int bnd = cums[sid0 + 1];

    const int r0 = rowBase + wave * 16 + kg * 4;
#pragma unroll
    for (int t = 0; t < 8; ++t) {
        const int col = t * 16 + m16;
        const float bv = bvec[col];
        float s0 = 0.f, q0 = 0.f, s1 = 0.f, q1 = 0.f;
#pragma unroll
        for (int j = 0; j < 4; ++j) {
            const int row = r0 + j;
            if (row < n) {
                const long long off = (long long)row * 128 + col;
                const float val = acc[t][j] + bv + input[off];
                x[off] = val;
                if (row < bnd) { s0 += val; q0 += val * val; }
                else           { s1 += val; q1 += val * val; }
            }
        }
        s0 += __shfl_xor(s0, 16, 64); s0 += __shfl_xor(s0, 32, 64);
        q0 += __shfl_xor(q0, 16, 64); q0 += __shfl_xor(q0, 32, 64);
        s1 += __shfl_xor(s1, 16, 64); s1 += __shfl_xor(s1, 32, 64);
        q1 += __shfl_xor(q1, 16, 64); q1 += __shfl_xor(q1, 32, 64);
        if (kg == 0) {
            atomicAdd(&s_sum[col], s0);
            atomicAdd(&s_sq[col], q0);
            if (s1 != 0.f || q1 != 0.f) {
                atomicAdd(&sums[(sid0 + 1) * 128 + col], s1);
                atomicAdd(&sumsq[(sid0 + 1) * 128 + col], q1);
            }
        }
    }
    __syncthreads();
    if (tid < 128) {
        atomicAdd(&sums[sid0 * 128 + tid], s_sum[tid]);
        atomicAdd(&sumsq[sid0 * 128 + tid], s_sq[tid]);
    }
}

// K6: sums -> mean, sumsq -> 1/(std+eps)  (unbiased, n-1)
__global__ __launch_bounds__(128) void finalize_stats_kernel(
    const int* __restrict__ cums, float* __restrict__ sums,
    float* __restrict__ sumsq)
{
    const int b = blockIdx.x;
    const int tid = threadIdx.x;
    const float cnt = (float)(cums[b + 1] - cums[b]);
    const float s = sums[b * 128 + tid];
    const float s2 = sumsq[b * 128 + tid];
    const float mean = s / cnt;
    float var = (s2 - s * mean) / (cnt - 1.f);
    var = fmaxf(var, 0.f);
    sums[b * 128 + tid] = mean;
    sumsq[b * 128 + tid] = 1.f / (sqrtf(var) + 1e-5f);
}

__global__ __launch_bounds__(256) void norm_kernel(
    const float* __restrict__ x, const float* __restrict__ mean,
    const float* __restrict__ istd, const int* __restrict__ cums, int nb,
    const float* __restrict__ gamma, const float* __restrict__ beta,
    float* __restrict__ out, int n)
{
    const long long gid = (long long)blockIdx.x * 256 + threadIdx.x;
    const int node = (int)(gid >> 5);
    if (node >= n) return;
    const int f4 = (int)(gid & 31);
    int lo = 0, hi = nb;
    while (hi - lo > 1) {
        const int mid = (lo + hi) >> 1;
        if (cums[mid] <= node) lo = mid; else hi = mid;
    }
    const float4 m = *(const float4*)&mean[lo * 128 + f4 * 4];
    const float4 is = *(const float4*)&istd[lo * 128 + f4 * 4];
    const float4 g = *(const float4*)&gamma[f4 * 4];
    const float4 bt = *(const float4*)&beta[f4 * 4];
    const float4 v = *(const float4*)&x[(long long)node * 128 + f4 * 4];
    float4 o;
    o.x = g.x * ((v.x - m.x) * is.x) + bt.x;
    o.y = g.y * ((v.y - m.y) * is.y) + bt.y;
    o.z = g.z * ((v.z - m.z) * is.z) + bt.z;
    o.w = g.w * ((v.w - m.w) * is.w) + bt.w;
    *(float4*)&out[(long long)node * 128 + f4 * 4] = o;
}

// ---------------------------------------------------------------------------
extern "C" void kernel_launch(void* const* d_in, const int* in_sizes, int n_in,
                              void* d_out, int out_size, void* d_ws, size_t ws_size,
                              hipStream_t stream) {
    const float* input   = (const float*)d_in[0];
    const float* h0      = (const float*)d_in[1];
    const int*   src     = (const int*)d_in[2];
    const int*   dst     = (const int*)d_in[3];
    const int*   cums    = (const int*)d_in[4];
    const int*   l_p     = (const int*)d_in[5];
    const float* lamda_p = (const float*)d_in[6];
    const float* alpha_p = (const float*)d_in[7];
    const float* W_fc    = (const float*)d_in[8];
    const float* attn_l  = (const float*)d_in[9];
    const float* attn_r  = (const float*)d_in[10];
    const float* gat_bias= (const float*)d_in[11];
    const float* W_comb  = (const float*)d_in[12];
    const float* gamma   = (const float*)d_in[13];
    const float* beta    = (const float*)d_in[14];

    const int n  = in_sizes[0] / 128;
    const int E  = in_sizes[2];
    const int nb = in_sizes[4] - 1;
    float* out = (float*)d_out;

    // workspace layout (all offsets 16B-aligned)
    char* ws = (char*)d_ws;
    size_t o = 0;
#define ALLOC(ptr, type, count)                                              \
    type* ptr = (type*)(ws + o); o = (o + (size_t)(count) * sizeof(type) + 15) & ~(size_t)15;
    ALLOC(h,        unsigned short, (size_t)n * 128)
    ALLOC(el,       float,          (size_t)n * 8)
    ALLOC(er,       float,          (size_t)n * 8)
    ALLOC(rst,      unsigned short, (size_t)n * 128)
    ALLOC(sums,     float,          (size_t)nb * 128)
    ALLOC(sumsq,    float,          (size_t)nb * 128)
    ALLOC(deg,      int,            (size_t)n)
    ALLOC(row_ptr,  int,            (size_t)n + 1)
    ALLOC(cursor,   int,            (size_t)n)
    ALLOC(blockSums,int,            128)
    ALLOC(srcs,     int,            (size_t)E)
    ALLOC(Wt_fc,    unsigned short, 144 * 128)
    ALLOC(Wt_cb,    unsigned short, 128 * 256)
    ALLOC(bvec,     float,          128)
#undef ALLOC

    hipMemsetAsync(deg, 0, (size_t)n * 4, stream);
    hipMemsetAsync(sums, 0, (size_t)nb * 128 * 4, stream);
    hipMemsetAsync(sumsq, 0, (size_t)nb * 128 * 4, stream);

    // --- prep (weights -> bf16 transposed; attn columns + GCNII/bias fold) ---
    prep_kernel<<<64, 256, 0, stream>>>(
        W_fc, attn_l, attn_r, W_comb, gat_bias, l_p, lamda_p, alpha_p,
        Wt_fc, Wt_cb, bvec);

    // --- CSR build ---
    hist_kernel<<<(E + 255) / 256, 256, 0, stream>>>(dst, deg, E);
    const int nblk1 = (n + 1023) / 1024;
    scan1_kernel<<<nblk1, 256, 0, stream>>>(deg, row_ptr, blockSums, n);
    scan2_kernel<<<1, 128, 0, stream>>>(blockSums, nblk1);
    scan3_kernel<<<(n + 255) / 256, 256, 0, stream>>>(row_ptr, cursor, blockSums, n, E);
    scatter_kernel<<<(E + 255) / 256, 256, 0, stream>>>(src, dst, cursor, srcs, E);

    // --- dense pipeline ---
    const int gemm_grid = (n + 63) / 64;
    fc_gemm_kernel<<<gemm_grid, 256, 0, stream>>>(input, Wt_fc, h, el, er, n);

    aggregate_kernel<<<(n + 3) / 4, 256, 0, stream>>>(
        el, er, h, row_ptr, srcs, rst, n);

    const size_t cb_lds = 128 * 264 * 2 + 256 * 4;   // Bs + s_sum/s_sq
    combine_gemm_kernel<<<gemm_grid, 256, cb_lds, stream>>>(
        rst, h0, input, Wt_cb, bvec, cums, nb, sums, sumsq, out, n);

    finalize_stats_kernel<<<nb, 128, 0, stream>>>(cums, sums, sumsq);

    const long long norm_threads = (long long)n * 32;
    norm_kernel<<<(int)((norm_threads + 255) / 256), 256, 0, stream>>>(
        out, sums, sumsq, cums, nb, gamma, beta, out, n);
}

// Round 16
// 229.441 us; speedup vs baseline: 1.1072x; 1.1072x over previous
//
#include <hip/hip_runtime.h>
#include <hip/hip_bf16.h>

#define NEG_SLOPE 0.2f

typedef short bf16x8 __attribute__((ext_vector_type(8)));
typedef float f32x4 __attribute__((ext_vector_type(4)));

__device__ __forceinline__ unsigned short f2bf(float f) {
    unsigned int u = __float_as_uint(f);
    unsigned int r = (u + 0x7fffu + ((u >> 16) & 1u)) >> 16;
    return (unsigned short)r;
}
__device__ __forceinline__ float bf2f(unsigned short h) {
    return __uint_as_float(((unsigned int)h) << 16);
}

// ---------------------------------------------------------------------------
// K0: prep. Wt_fc[144][128] = [W_fc^T ; (W_fc@attn_l)^T ; (W_fc@attn_r)^T].
// Wt_cb[128][256] = theta*W_comb^T + c1*I(k==c) + c2*I(k==c+128).
// bvec[128] = theta*(gat_bias @ W_comb_top) + c1*gat_bias.
// ---------------------------------------------------------------------------
__global__ __launch_bounds__(256) void prep_kernel(
    const float* __restrict__ W_fc, const float* __restrict__ attn_l,
    const float* __restrict__ attn_r, const float* __restrict__ W_comb,
    const float* __restrict__ gat_bias,
    const int* __restrict__ l_p, const float* __restrict__ lamda_p,
    const float* __restrict__ alpha_p,
    unsigned short* __restrict__ Wt_fc, unsigned short* __restrict__ Wt_cb,
    float* __restrict__ bvec)
{
    const float alpha = alpha_p[0];
    const float theta = fminf(1.0f, logf(lamda_p[0] / (float)l_p[0] + 1.0f));
    const float c1 = (1.f - theta) * (1.f - alpha);
    const float c2 = (1.f - theta) * alpha;

    const int t = blockIdx.x * 256 + threadIdx.x;
    const int stride = gridDim.x * 256;
    for (int i = t; i < 128 * 128; i += stride) {
        const int c = i >> 7, k = i & 127;
        Wt_fc[c * 128 + k] = f2bf(W_fc[k * 128 + c]);
    }
    for (int i = t; i < 8 * 128; i += stride) {
        const int hd = i >> 7, k = i & 127;
        float sl = 0.f, sr = 0.f;
        for (int d = 0; d < 16; ++d) {
            const float w = W_fc[k * 128 + hd * 16 + d];
            sl += w * attn_l[hd * 16 + d];
            sr += w * attn_r[hd * 16 + d];
        }
        Wt_fc[(128 + hd) * 128 + k] = f2bf(sl);
        Wt_fc[(136 + hd) * 128 + k] = f2bf(sr);
    }
    for (int i = t; i < 128 * 256; i += stride) {
        const int c = i >> 8, k = i & 255;
        float w = theta * W_comb[k * 128 + c];
        if (k == c) w += c1;
        if (k == c + 128) w += c2;
        Wt_cb[c * 256 + k] = f2bf(w);
    }
    for (int c = t; c < 128; c += stride) {
        float s = c1 * gat_bias[c];
        for (int k = 0; k < 128; ++k)
            s += theta * gat_bias[k] * W_comb[k * 128 + c];
        bvec[c] = s;
    }
}

// ---------------------------------------------------------------------------
// K1: h = input @ W_fc via bf16 MFMA, el/er as output cols 128..143.
// 512 threads / 128-row tile (8 waves x 16 rows): round-12 sync pattern
// (BK=32 double-buffer, one barrier/phase) but each barrier now covers
// 2x MFMA work and blocks halve -> more resident waves hide phase latency.
// ---------------------------------------------------------------------------
__global__ __launch_bounds__(512) void fc_gemm_kernel(
    const float* __restrict__ A, const unsigned short* __restrict__ Wt,
    unsigned short* __restrict__ h, float* __restrict__ el,
    float* __restrict__ er, int n)
{
    __shared__ unsigned short Bs[2][144][36];
    const int tid = threadIdx.x;
    const int wave = tid >> 6;
    const int lane = tid & 63;
    const int m16 = lane & 15;
    const int kg = lane >> 4;
    const int rowBase = blockIdx.x * 128;

    // A in registers: all 4 chunks, issued first.
    int arow = rowBase + wave * 16 + m16;
    if (arow >= n) arow = n - 1;
    const long long aoff = (long long)arow * 128;
    bf16x8 af[4];
#pragma unroll
    for (int ci = 0; ci < 4; ++ci) {
        const float4 v0 = *(const float4*)&A[aoff + ci * 32 + kg * 8];
        const float4 v1 = *(const float4*)&A[aoff + ci * 32 + kg * 8 + 4];
        bf16x8 pk;
        pk[0] = (short)f2bf(v0.x); pk[1] = (short)f2bf(v0.y);
        pk[2] = (short)f2bf(v0.z); pk[3] = (short)f2bf(v0.w);
        pk[4] = (short)f2bf(v1.x); pk[5] = (short)f2bf(v1.y);
        pk[6] = (short)f2bf(v1.z); pk[7] = (short)f2bf(v1.w);
        af[ci] = pk;
    }

    // B staging: per phase 144 rows x 4 bf16x8-units = 576 units; 512
    // threads stage 1 unit each, threads 0..63 a second (rows 128..143).
    const int rB = tid >> 2;
    const int pB = tid & 3;
    bf16x8 vb0, w0;
#define FC_BLOAD(ci)                                                         \
    {                                                                        \
        const int kc = (ci) * 32;                                            \
        vb0 = *(const bf16x8*)&Wt[rB * 128 + kc + pB * 8];                   \
        if (tid < 64)                                                        \
            w0 = *(const bf16x8*)&Wt[(128 + rB) * 128 + kc + pB * 8];        \
    }
#define FC_BWRITE(buf)                                                       \
    {                                                                        \
        *(bf16x8*)&Bs[buf][rB][pB * 8] = vb0;                                \
        if (tid < 64)                                                        \
            *(bf16x8*)&Bs[buf][128 + rB][pB * 8] = w0;                       \
    }

    f32x4 acc[9];
#pragma unroll
    for (int t = 0; t < 9; ++t) acc[t] = (f32x4){0.f, 0.f, 0.f, 0.f};

    FC_BLOAD(0)
    FC_BWRITE(0)
    __syncthreads();

#pragma unroll
    for (int ci = 0; ci < 4; ++ci) {
        const int cur = ci & 1;
        if (ci < 3) FC_BLOAD(ci + 1)
#pragma unroll
        for (int t = 0; t < 9; ++t) {
            const bf16x8 bfrag = *(const bf16x8*)&Bs[cur][t * 16 + m16][kg * 8];
            acc[t] = __builtin_amdgcn_mfma_f32_16x16x32_bf16(af[ci], bfrag, acc[t], 0, 0, 0);
        }
        if (ci < 3) {
            FC_BWRITE(cur ^ 1)
            __syncthreads();
        }
    }
#undef FC_BLOAD
#undef FC_BWRITE

    const int r0 = rowBase + wave * 16 + kg * 4;
#pragma unroll
    for (int t = 0; t < 8; ++t) {
#pragma unroll
        for (int j = 0; j < 4; ++j) {
            const int row = r0 + j;
            if (row < n)
                h[(long long)row * 128 + t * 16 + m16] = f2bf(acc[t][j]);
        }
    }
#pragma unroll
    for (int j = 0; j < 4; ++j) {
        const int row = r0 + j;
        if (row < n) {
            const float v = acc[8][j];
            if (m16 < 8) el[(long long)row * 8 + m16] = v;
            else         er[(long long)row * 8 + (m16 - 8)] = v;
        }
    }
}

// ---------------------------------------------------------------------------
// CSR build: histogram -> 2-level exclusive scan -> scatter src ids by dst.
// ---------------------------------------------------------------------------
__global__ __launch_bounds__(256) void hist_kernel(
    const int* __restrict__ dst, int* __restrict__ deg, int E)
{
    const int i = blockIdx.x * 256 + threadIdx.x;
    if (i < E) atomicAdd(&deg[dst[i]], 1);
}

__global__ __launch_bounds__(256) void scan1_kernel(
    const int* __restrict__ deg, int* __restrict__ row,
    int* __restrict__ blockSums, int n)
{
    __shared__ int sdata[256];
    const int t = threadIdx.x;
    const int base = blockIdx.x * 1024 + t * 4;
    int v[4];
    int tot = 0;
#pragma unroll
    for (int j = 0; j < 4; ++j) {
        v[j] = (base + j < n) ? deg[base + j] : 0;
        tot += v[j];
    }
    sdata[t] = tot;
    __syncthreads();
    for (int off = 1; off < 256; off <<= 1) {
        const int x = (t >= off) ? sdata[t - off] : 0;
        __syncthreads();
        sdata[t] += x;
        __syncthreads();
    }
    if (t == 255) blockSums[blockIdx.x] = sdata[255];
    int run = sdata[t] - tot;
#pragma unroll
    for (int j = 0; j < 4; ++j) {
        if (base + j < n) row[base + j] = run;
        run += v[j];
    }
}

__global__ __launch_bounds__(128) void scan2_kernel(
    int* __restrict__ blockSums, int nb)
{
    __shared__ int sdata[128];
    const int t = threadIdx.x;
    const int v = (t < nb) ? blockSums[t] : 0;
    sdata[t] = v;
    __syncthreads();
    for (int off = 1; off < 128; off <<= 1) {
        const int x = (t >= off) ? sdata[t - off] : 0;
        __syncthreads();
        sdata[t] += x;
        __syncthreads();
    }
    if (t < nb) blockSums[t] = sdata[t] - v;
}

__global__ __launch_bounds__(256) void scan3_kernel(
    int* __restrict__ row, int* __restrict__ cursor,
    const int* __restrict__ blockSums, int n, int E)
{
    const int i = blockIdx.x * 256 + threadIdx.x;
    if (i == 0) row[n] = E;
    if (i >= n) return;
    const int r = row[i] + blockSums[i >> 10];
    row[i] = r;
    cursor[i] = r;
}

__global__ __launch_bounds__(256) void scatter_kernel(
    const int* __restrict__ src, const int* __restrict__ dst,
    int* __restrict__ cursor, int* __restrict__ srcs, int E)
{
    const int i = blockIdx.x * 256 + threadIdx.x;
    if (i >= E) return;
    const int pos = atomicAdd(&cursor[dst[i]], 1);
    srcs[pos] = src[i];
}

// ---------------------------------------------------------------------------
// K3: aggregate. One wave per dst node, ushort2/lane, one head per lane,
// cooperative srcs batch + shfl broadcast, x2 unroll. rst written bf16.
// ---------------------------------------------------------------------------
__global__ __launch_bounds__(256) void aggregate_kernel(
    const float* __restrict__ el, const float* __restrict__ er,
    const unsigned short* __restrict__ h, const int* __restrict__ row,
    const int* __restrict__ srcs, unsigned short* __restrict__ rst, int n)
{
    const int d = blockIdx.x * 4 + (threadIdx.x >> 6);
    const int lane = threadIdx.x & 63;
    if (d >= n) return;
    const int start = row[d], end = row[d + 1];
    const int hd = lane >> 3;
    const float erd = er[(long long)d * 8 + hd];

    float acc0 = 0.f, acc1 = 0.f, den = 0.f;
    for (int p = start; p < end; p += 64) {
        const int cnt = min(64, end - p);
        const int sv = srcs[p + (lane < cnt ? lane : cnt - 1)];
        int j = 0;
        for (; j + 1 < cnt; j += 2) {
            const int s0 = __shfl(sv, j);
            const int s1 = __shfl(sv, j + 1);
            const float g0 = el[(long long)s0 * 8 + hd];
            const float g1 = el[(long long)s1 * 8 + hd];
            const unsigned int u0 = *(const unsigned int*)&h[(long long)s0 * 128 + lane * 2];
            const unsigned int u1 = *(const unsigned int*)&h[(long long)s1 * 128 + lane * 2];
            float e0 = g0 + erd; e0 = e0 >= 0.f ? e0 : NEG_SLOPE * e0;
            float e1 = g1 + erd; e1 = e1 >= 0.f ? e1 : NEG_SLOPE * e1;
            const float w0 = __expf(e0);
            const float w1 = __expf(e1);
            den += w0 + w1;
            acc0 += w0 * __uint_as_float(u0 << 16)
                  + w1 * __uint_as_float(u1 << 16);
            acc1 += w0 * __uint_as_float(u0 & 0xffff0000u)
                  + w1 * __uint_as_float(u1 & 0xffff0000u);
        }
        if (j < cnt) {
            const int s0 = __shfl(sv, j);
            const unsigned int u0 = *(const unsigned int*)&h[(long long)s0 * 128 + lane * 2];
            float e0 = el[(long long)s0 * 8 + hd] + erd;
            e0 = e0 >= 0.f ? e0 : NEG_SLOPE * e0;
            const float w0 = __expf(e0);
            den += w0;
            acc0 += w0 * __uint_as_float(u0 << 16);
            acc1 += w0 * __uint_as_float(u0 & 0xffff0000u);
        }
    }
    ushort2 o;
    if (end > start) {
        const float inv = 1.f / den;
        o.x = f2bf(acc0 * inv);
        o.y = f2bf(acc1 * inv);
    } else {
        o.x = 0; o.y = 0;
    }
    *(ushort2*)&rst[(long long)d * 128 + lane * 2] = o;
}

// ---------------------------------------------------------------------------
// K4: GCNII combine via bf16 MFMA, fully folded: out = acc + bvec + input.
// 512 threads / 128-row tile (8 waves x 16 rows). Round-12 sync pattern:
// BK=32 double-buffer, one barrier per phase; A-fragments in registers.
// Fused GraphNorm stats in the epilogue.
// ---------------------------------------------------------------------------
__global__ __launch_bounds__(512) void combine_gemm_kernel(
    const unsigned short* __restrict__ rst, const float* __restrict__ h0,
    const float* __restrict__ input, const unsigned short* __restrict__ Wt,
    const float* __restrict__ bvec, const int* __restrict__ cums, int nb,
    float* __restrict__ sums, float* __restrict__ sumsq,
    float* __restrict__ x, int n)
{
    __shared__ unsigned short Bs[2][128][36];
    __shared__ float s_sum[128], s_sq[128];
    const int tid = threadIdx.x;
    const int wave = tid >> 6;
    const int lane = tid & 63;
    const int m16 = lane & 15;
    const int kg = lane >> 4;
    const int rowBase = blockIdx.x * 128;

    if (tid < 128) { s_sum[tid] = 0.f; s_sq[tid] = 0.f; }

    // A in registers: 8 chunks (rst 0-3 direct bf16, h0 4-7 cvt).
    int arow = rowBase + wave * 16 + m16;
    if (arow >= n) arow = n - 1;
    const long long aoff = (long long)arow * 128;
    bf16x8 af[8];
#pragma unroll
    for (int ci = 0; ci < 4; ++ci)
        af[ci] = *(const bf16x8*)&rst[aoff + ci * 32 + kg * 8];
#pragma unroll
    for (int ci = 0; ci < 4; ++ci) {
        const float4 v0 = *(const float4*)&h0[aoff + ci * 32 + kg * 8];
        const float4 v1 = *(const float4*)&h0[aoff + ci * 32 + kg * 8 + 4];
        bf16x8 pk;
        pk[0] = (short)f2bf(v0.x); pk[1] = (short)f2bf(v0.y);
        pk[2] = (short)f2bf(v0.z); pk[3] = (short)f2bf(v0.w);
        pk[4] = (short)f2bf(v1.x); pk[5] = (short)f2bf(v1.y);
        pk[6] = (short)f2bf(v1.z); pk[7] = (short)f2bf(v1.w);
        af[4 + ci] = pk;
    }

    // B staging: per phase 128 rows x 4 units = 512 units = 1 unit/thread.
    const int rB = tid >> 2;
    const int pB = tid & 3;
    bf16x8 vb0;
#define CB_BLOAD(ci)                                                          \
    { vb0 = *(const bf16x8*)&Wt[rB * 256 + (ci) * 32 + pB * 8]; }
#define CB_BWRITE(buf)                                                        \
    { *(bf16x8*)&Bs[buf][rB][pB * 8] = vb0; }

    f32x4 acc[8];
#pragma unroll
    for (int t = 0; t < 8; ++t) acc[t] = (f32x4){0.f, 0.f, 0.f, 0.f};

    CB_BLOAD(0)
    CB_BWRITE(0)
    __syncthreads();

#pragma unroll
    for (int ci = 0; ci < 8; ++ci) {
        const int cur = ci & 1;
        if (ci < 7) CB_BLOAD(ci + 1)
#pragma unroll
        for (int t = 0; t < 8; ++t) {
            const bf16x8 bfrag = *(const bf16x8*)&Bs[cur][t * 16 + m16][kg * 8];
            acc[t] = __builtin_amdgcn_mfma_f32_16x16x32_bf16(af[ci], bfrag, acc[t], 0, 0, 0);
        }
        if (ci < 7) {
            CB_BWRITE(cur ^ 1)
            __syncthreads();
        }
    }
#undef CB_BLOAD
#undef CB_BWRITE

    // ---- epilogue: out = acc + bvec + input, fused GraphNorm partials ----
    int lo = 0, hi = nb;
    while (hi - lo > 1) {
        const int mid = (lo + hi) >> 1;
        if (cums[mid] <= rowBase) lo = mid; else hi = mid;
    }
    const int sid0 = lo;
    const int bnd = cums[sid0 + 1];

    const int r0 = rowBase + wave * 16 + kg * 4;
#pragma unroll
    for (int t = 0; t < 8; ++t) {
        const int col = t * 16 + m16;
        const float bv = bvec[col];
        float s0 = 0.f, q0 = 0.f, s1 = 0.f, q1 = 0.f;
#pragma unroll
        for (int j = 0; j < 4; ++j) {
            const int row = r0 + j;
            if (row < n) {
                const long long off = (long long)row * 128 + col;
                const float val = acc[t][j] + bv + input[off];
                x[off] = val;
                if (row < bnd) { s0 += val; q0 += val * val; }
                else           { s1 += val; q1 += val * val; }
            }
        }
        s0 += __shfl_xor(s0, 16, 64); s0 += __shfl_xor(s0, 32, 64);
        q0 += __shfl_xor(q0, 16, 64); q0 += __shfl_xor(q0, 32, 64);
        s1 += __shfl_xor(s1, 16, 64); s1 += __shfl_xor(s1, 32, 64);
        q1 += __shfl_xor(q1, 16, 64); q1 += __shfl_xor(q1, 32, 64);
        if (kg == 0) {
            atomicAdd(&s_sum[col], s0);
            atomicAdd(&s_sq[col], q0);
            if (s1 != 0.f || q1 != 0.f) {
                atomicAdd(&sums[(sid0 + 1) * 128 + col], s1);
                atomicAdd(&sumsq[(sid0 + 1) * 128 + col], q1);
            }
        }
    }
    __syncthreads();
    if (tid < 128) {
        atomicAdd(&sums[sid0 * 128 + tid], s_sum[tid]);
        atomicAdd(&sumsq[sid0 * 128 + tid], s_sq[tid]);
    }
}

// K6: sums -> mean, sumsq -> 1/(std+eps)  (unbiased, n-1)
__global__ __launch_bounds__(128) void finalize_stats_kernel(
    const int* __restrict__ cums, float* __restrict__ sums,
    float* __restrict__ sumsq)
{
    const int b = blockIdx.x;
    const int tid = threadIdx.x;
    const float cnt = (float)(cums[b + 1] - cums[b]);
    const float s = sums[b * 128 + tid];
    const float s2 = sumsq[b * 128 + tid];
    const float mean = s / cnt;
    float var = (s2 - s * mean) / (cnt - 1.f);
    var = fmaxf(var, 0.f);
    sums[b * 128 + tid] = mean;
    sumsq[b * 128 + tid] = 1.f / (sqrtf(var) + 1e-5f);
}

__global__ __launch_bounds__(256) void norm_kernel(
    const float* __restrict__ x, const float* __restrict__ mean,
    const float* __restrict__ istd, const int* __restrict__ cums, int nb,
    const float* __restrict__ gamma, const float* __restrict__ beta,
    float* __restrict__ out, int n)
{
    const long long gid = (long long)blockIdx.x * 256 + threadIdx.x;
    const int node = (int)(gid >> 5);
    if (node >= n) return;
    const int f4 = (int)(gid & 31);
    int lo = 0, hi = nb;
    while (hi - lo > 1) {
        const int mid = (lo + hi) >> 1;
        if (cums[mid] <= node) lo = mid; else hi = mid;
    }
    const float4 m = *(const float4*)&mean[lo * 128 + f4 * 4];
    const float4 is = *(const float4*)&istd[lo * 128 + f4 * 4];
    const float4 g = *(const float4*)&gamma[f4 * 4];
    const float4 bt = *(const float4*)&beta[f4 * 4];
    const float4 v = *(const float4*)&x[(long long)node * 128 + f4 * 4];
    float4 o;
    o.x = g.x * ((v.x - m.x) * is.x) + bt.x;
    o.y = g.y * ((v.y - m.y) * is.y) + bt.y;
    o.z = g.z * ((v.z - m.z) * is.z) + bt.z;
    o.w = g.w * ((v.w - m.w) * is.w) + bt.w;
    *(float4*)&out[(long long)node * 128 + f4 * 4] = o;
}

// ---------------------------------------------------------------------------
extern "C" void kernel_launch(void* const* d_in, const int* in_sizes, int n_in,
                              void* d_out, int out_size, void* d_ws, size_t ws_size,
                              hipStream_t stream) {
    const float* input   = (const float*)d_in[0];
    const float* h0      = (const float*)d_in[1];
    const int*   src     = (const int*)d_in[2];
    const int*   dst     = (const int*)d_in[3];
    const int*   cums    = (const int*)d_in[4];
    const int*   l_p     = (const int*)d_in[5];
    const float* lamda_p = (const float*)d_in[6];
    const float* alpha_p = (const float*)d_in[7];
    const float* W_fc    = (const float*)d_in[8];
    const float* attn_l  = (const float*)d_in[9];
    const float* attn_r  = (const float*)d_in[10];
    const float* gat_bias= (const float*)d_in[11];
    const float* W_comb  = (const float*)d_in[12];
    const float* gamma   = (const float*)d_in[13];
    const float* beta    = (const float*)d_in[14];

    const int n  = in_sizes[0] / 128;
    const int E  = in_sizes[2];
    const int nb = in_sizes[4] - 1;
    float* out = (float*)d_out;

    // workspace layout (all offsets 16B-aligned; sums/sumsq/deg contiguous
    // for a single memset)
    char* ws = (char*)d_ws;
    size_t o = 0;
#define ALLOC(ptr, type, count)                                              \
    type* ptr = (type*)(ws + o); o = (o + (size_t)(count) * sizeof(type) + 15) & ~(size_t)15;
    ALLOC(h,        unsigned short, (size_t)n * 128)
    ALLOC(el,       float,          (size_t)n * 8)
    ALLOC(er,       float,          (size_t)n * 8)
    ALLOC(rst,      unsigned short, (size_t)n * 128)
    ALLOC(sums,     float,          (size_t)nb * 128)
    ALLOC(sumsq,    float,          (size_t)nb * 128)
    ALLOC(deg,      int,            (size_t)n)
    ALLOC(row_ptr,  int,            (size_t)n + 1)
    ALLOC(cursor,   int,            (size_t)n)
    ALLOC(blockSums,int,            128)
    ALLOC(srcs,     int,            (size_t)E)
    ALLOC(Wt_fc,    unsigned short, 144 * 128)
    ALLOC(Wt_cb,    unsigned short, 128 * 256)
    ALLOC(bvec,     float,          128)
#undef ALLOC

    // single memset covering sums + sumsq + deg (contiguous)
    hipMemsetAsync(sums, 0, (char*)(deg + n) - (char*)sums, stream);

    // --- prep (weights -> bf16 transposed; attn columns + GCNII/bias fold) ---
    prep_kernel<<<64, 256, 0, stream>>>(
        W_fc, attn_l, attn_r, W_comb, gat_bias, l_p, lamda_p, alpha_p,
        Wt_fc, Wt_cb, bvec);

    // --- CSR build ---
    hist_kernel<<<(E + 255) / 256, 256, 0, stream>>>(dst, deg, E);
    const int nblk1 = (n + 1023) / 1024;
    scan1_kernel<<<nblk1, 256, 0, stream>>>(deg, row_ptr, blockSums, n);
    scan2_kernel<<<1, 128, 0, stream>>>(blockSums, nblk1);
    scan3_kernel<<<(n + 255) / 256, 256, 0, stream>>>(row_ptr, cursor, blockSums, n, E);
    scatter_kernel<<<(E + 255) / 256, 256, 0, stream>>>(src, dst, cursor, srcs, E);

    // --- dense pipeline ---
    const int gemm_grid = (n + 127) / 128;
    fc_gemm_kernel<<<gemm_grid, 512, 0, stream>>>(input, Wt_fc, h, el, er, n);

    aggregate_kernel<<<(n + 3) / 4, 256, 0, stream>>>(
        el, er, h, row_ptr, srcs, rst, n);

    combine_gemm_kernel<<<gemm_grid, 512, 0, stream>>>(
        rst, h0, input, Wt_cb, bvec, cums, nb, sums, sumsq, out, n);

    finalize_stats_kernel<<<nb, 128, 0, stream>>>(cums, sums, sumsq);

    const long long norm_threads = (long long)n * 32;
    norm_kernel<<<(int)((norm_threads + 255) / 256), 256, 0, stream>>>(
        out, sums, sumsq, cums, nb, gamma, beta, out, n);
}

// Round 18
// 221.284 us; speedup vs baseline: 1.1480x; 1.0369x over previous
//
#include <hip/hip_runtime.h>
#include <hip/hip_bf16.h>

#define NEG_SLOPE 0.2f

typedef short bf16x8 __attribute__((ext_vector_type(8)));
typedef float f32x4 __attribute__((ext_vector_type(4)));

__device__ __forceinline__ unsigned short f2bf(float f) {
    unsigned int u = __float_as_uint(f);
    unsigned int r = (u + 0x7fffu + ((u >> 16) & 1u)) >> 16;
    return (unsigned short)r;
}
__device__ __forceinline__ float bf2f(unsigned short h) {
    return __uint_as_float(((unsigned int)h) << 16);
}

// ---------------------------------------------------------------------------
// K0: prep. Wt_fc[144][128] = [W_fc^T ; (W_fc@attn_l)^T ; (W_fc@attn_r)^T].
// Wt_cb[128][256] = theta*W_comb^T + c1*I(k==c) + c2*I(k==c+128).
// bvec[128] = theta*(gat_bias @ W_comb_top) + c1*gat_bias.
// ---------------------------------------------------------------------------
__global__ __launch_bounds__(256) void prep_kernel(
    const float* __restrict__ W_fc, const float* __restrict__ attn_l,
    const float* __restrict__ attn_r, const float* __restrict__ W_comb,
    const float* __restrict__ gat_bias,
    const int* __restrict__ l_p, const float* __restrict__ lamda_p,
    const float* __restrict__ alpha_p,
    unsigned short* __restrict__ Wt_fc, unsigned short* __restrict__ Wt_cb,
    float* __restrict__ bvec)
{
    const float alpha = alpha_p[0];
    const float theta = fminf(1.0f, logf(lamda_p[0] / (float)l_p[0] + 1.0f));
    const float c1 = (1.f - theta) * (1.f - alpha);
    const float c2 = (1.f - theta) * alpha;

    const int t = blockIdx.x * 256 + threadIdx.x;
    const int stride = gridDim.x * 256;
    for (int i = t; i < 128 * 128; i += stride) {
        const int c = i >> 7, k = i & 127;
        Wt_fc[c * 128 + k] = f2bf(W_fc[k * 128 + c]);
    }
    for (int i = t; i < 8 * 128; i += stride) {
        const int hd = i >> 7, k = i & 127;
        float sl = 0.f, sr = 0.f;
        for (int d = 0; d < 16; ++d) {
            const float w = W_fc[k * 128 + hd * 16 + d];
            sl += w * attn_l[hd * 16 + d];
            sr += w * attn_r[hd * 16 + d];
        }
        Wt_fc[(128 + hd) * 128 + k] = f2bf(sl);
        Wt_fc[(136 + hd) * 128 + k] = f2bf(sr);
    }
    for (int i = t; i < 128 * 256; i += stride) {
        const int c = i >> 8, k = i & 255;
        float w = theta * W_comb[k * 128 + c];
        if (k == c) w += c1;
        if (k == c + 128) w += c2;
        Wt_cb[c * 256 + k] = f2bf(w);
    }
    for (int c = t; c < 128; c += stride) {
        float s = c1 * gat_bias[c];
        for (int k = 0; k < 128; ++k)
            s += theta * gat_bias[k] * W_comb[k * 128 + c];
        bvec[c] = s;
    }
}

// ---------------------------------------------------------------------------
// K1: h = input @ W_fc via bf16 MFMA, el/er as output cols 128..143.
// A-fragments (4 chunks) in registers, loaded once. B double-buffered in
// LDS, one barrier per BK=32 phase (round-12 structure, session best).
// ---------------------------------------------------------------------------
__global__ __launch_bounds__(256) void fc_gemm_kernel(
    const float* __restrict__ A, const unsigned short* __restrict__ Wt,
    unsigned short* __restrict__ h, float* __restrict__ el,
    float* __restrict__ er, int n)
{
    __shared__ unsigned short Bs[2][144][36];
    const int tid = threadIdx.x;
    const int wave = tid >> 6;
    const int lane = tid & 63;
    const int m16 = lane & 15;
    const int kg = lane >> 4;
    const int rowBase = blockIdx.x * 64;

    int arow = rowBase + wave * 16 + m16;
    if (arow >= n) arow = n - 1;
    const long long aoff = (long long)arow * 128;
    bf16x8 af[4];
#pragma unroll
    for (int ci = 0; ci < 4; ++ci) {
        const float4 v0 = *(const float4*)&A[aoff + ci * 32 + kg * 8];
        const float4 v1 = *(const float4*)&A[aoff + ci * 32 + kg * 8 + 4];
        bf16x8 pk;
        pk[0] = (short)f2bf(v0.x); pk[1] = (short)f2bf(v0.y);
        pk[2] = (short)f2bf(v0.z); pk[3] = (short)f2bf(v0.w);
        pk[4] = (short)f2bf(v1.x); pk[5] = (short)f2bf(v1.y);
        pk[6] = (short)f2bf(v1.z); pk[7] = (short)f2bf(v1.w);
        af[ci] = pk;
    }

    const int rB = tid >> 1;
    const int p0 = (tid & 1) * 2;
    const bool hasU2 = tid < 32;
    const int rB2 = 128 + (tid >> 1);

    bf16x8 vb0, vb1, w0, w1;
#define FC_BLOAD(ci)                                                         \
    {                                                                        \
        const int kc = (ci) * 32;                                            \
        vb0 = *(const bf16x8*)&Wt[rB * 128 + kc + p0 * 8];                   \
        vb1 = *(const bf16x8*)&Wt[rB * 128 + kc + p0 * 8 + 8];               \
        if (hasU2) {                                                         \
            w0 = *(const bf16x8*)&Wt[rB2 * 128 + kc + p0 * 8];               \
            w1 = *(const bf16x8*)&Wt[rB2 * 128 + kc + p0 * 8 + 8];           \
        }                                                                    \
    }
#define FC_BWRITE(buf)                                                       \
    {                                                                        \
        *(bf16x8*)&Bs[buf][rB][p0 * 8] = vb0;                                \
        *(bf16x8*)&Bs[buf][rB][p0 * 8 + 8] = vb1;                            \
        if (hasU2) {                                                         \
            *(bf16x8*)&Bs[buf][rB2][p0 * 8] = w0;                            \
            *(bf16x8*)&Bs[buf][rB2][p0 * 8 + 8] = w1;                        \
        }                                                                    \
    }

    f32x4 acc[9];
#pragma unroll
    for (int t = 0; t < 9; ++t) acc[t] = (f32x4){0.f, 0.f, 0.f, 0.f};

    FC_BLOAD(0)
    FC_BWRITE(0)
    __syncthreads();

#pragma unroll
    for (int ci = 0; ci < 4; ++ci) {
        const int cur = ci & 1;
        if (ci < 3) FC_BLOAD(ci + 1)
#pragma unroll
        for (int t = 0; t < 9; ++t) {
            const bf16x8 bfrag = *(const bf16x8*)&Bs[cur][t * 16 + m16][kg * 8];
            acc[t] = __builtin_amdgcn_mfma_f32_16x16x32_bf16(af[ci], bfrag, acc[t], 0, 0, 0);
        }
        if (ci < 3) {
            FC_BWRITE(cur ^ 1)
            __syncthreads();
        }
    }
#undef FC_BLOAD
#undef FC_BWRITE

    const int r0 = rowBase + wave * 16 + kg * 4;
#pragma unroll
    for (int t = 0; t < 8; ++t) {
#pragma unroll
        for (int j = 0; j < 4; ++j) {
            const int row = r0 + j;
            if (row < n)
                h[(long long)row * 128 + t * 16 + m16] = f2bf(acc[t][j]);
        }
    }
#pragma unroll
    for (int j = 0; j < 4; ++j) {
        const int row = r0 + j;
        if (row < n) {
            const float v = acc[8][j];
            if (m16 < 8) el[(long long)row * 8 + m16] = v;
            else         er[(long long)row * 8 + (m16 - 8)] = v;
        }
    }
}

// ---------------------------------------------------------------------------
// CSR build: histogram -> 2-level exclusive scan -> scatter src ids by dst.
// ---------------------------------------------------------------------------
__global__ __launch_bounds__(256) void hist_kernel(
    const int* __restrict__ dst, int* __restrict__ deg, int E)
{
    const int i = blockIdx.x * 256 + threadIdx.x;
    if (i < E) atomicAdd(&deg[dst[i]], 1);
}

__global__ __launch_bounds__(256) void scan1_kernel(
    const int* __restrict__ deg, int* __restrict__ row,
    int* __restrict__ blockSums, int n)
{
    __shared__ int sdata[256];
    const int t = threadIdx.x;
    const int base = blockIdx.x * 1024 + t * 4;
    int v[4];
    int tot = 0;
#pragma unroll
    for (int j = 0; j < 4; ++j) {
        v[j] = (base + j < n) ? deg[base + j] : 0;
        tot += v[j];
    }
    sdata[t] = tot;
    __syncthreads();
    for (int off = 1; off < 256; off <<= 1) {
        const int x = (t >= off) ? sdata[t - off] : 0;
        __syncthreads();
        sdata[t] += x;
        __syncthreads();
    }
    if (t == 255) blockSums[blockIdx.x] = sdata[255];
    int run = sdata[t] - tot;
#pragma unroll
    for (int j = 0; j < 4; ++j) {
        if (base + j < n) row[base + j] = run;
        run += v[j];
    }
}

__global__ __launch_bounds__(128) void scan2_kernel(
    int* __restrict__ blockSums, int nb)
{
    __shared__ int sdata[128];
    const int t = threadIdx.x;
    const int v = (t < nb) ? blockSums[t] : 0;
    sdata[t] = v;
    __syncthreads();
    for (int off = 1; off < 128; off <<= 1) {
        const int x = (t >= off) ? sdata[t - off] : 0;
        __syncthreads();
        sdata[t] += x;
        __syncthreads();
    }
    if (t < nb) blockSums[t] = sdata[t] - v;
}

__global__ __launch_bounds__(256) void scan3_kernel(
    int* __restrict__ row, int* __restrict__ cursor,
    const int* __restrict__ blockSums, int n, int E)
{
    const int i = blockIdx.x * 256 + threadIdx.x;
    if (i == 0) row[n] = E;
    if (i >= n) return;
    const int r = row[i] + blockSums[i >> 10];
    row[i] = r;
    cursor[i] = r;
}

__global__ __launch_bounds__(256) void scatter_kernel(
    const int* __restrict__ src, const int* __restrict__ dst,
    int* __restrict__ cursor, int* __restrict__ srcs, int E)
{
    const int i = blockIdx.x * 256 + threadIdx.x;
    if (i >= E) return;
    const int pos = atomicAdd(&cursor[dst[i]], 1);
    srcs[pos] = src[i];
}

// ---------------------------------------------------------------------------
// K3: aggregate. One wave per dst node, ushort2/lane, one head per lane,
// cooperative srcs batch + shfl broadcast, x2 unroll. rst written bf16.
// ---------------------------------------------------------------------------
__global__ __launch_bounds__(256) void aggregate_kernel(
    const float* __restrict__ el, const float* __restrict__ er,
    const unsigned short* __restrict__ h, const int* __restrict__ row,
    const int* __restrict__ srcs, unsigned short* __restrict__ rst, int n)
{
    const int d = blockIdx.x * 4 + (threadIdx.x >> 6);
    const int lane = threadIdx.x & 63;
    if (d >= n) return;
    const int start = row[d], end = row[d + 1];
    const int hd = lane >> 3;
    const float erd = er[(long long)d * 8 + hd];

    float acc0 = 0.f, acc1 = 0.f, den = 0.f;
    for (int p = start; p < end; p += 64) {
        const int cnt = min(64, end - p);
        const int sv = srcs[p + (lane < cnt ? lane : cnt - 1)];
        int j = 0;
        for (; j + 1 < cnt; j += 2) {
            const int s0 = __shfl(sv, j);
            const int s1 = __shfl(sv, j + 1);
            const float g0 = el[(long long)s0 * 8 + hd];
            const float g1 = el[(long long)s1 * 8 + hd];
            const unsigned int u0 = *(const unsigned int*)&h[(long long)s0 * 128 + lane * 2];
            const unsigned int u1 = *(const unsigned int*)&h[(long long)s1 * 128 + lane * 2];
            float e0 = g0 + erd; e0 = e0 >= 0.f ? e0 : NEG_SLOPE * e0;
            float e1 = g1 + erd; e1 = e1 >= 0.f ? e1 : NEG_SLOPE * e1;
            const float w0 = __expf(e0);
            const float w1 = __expf(e1);
            den += w0 + w1;
            acc0 += w0 * __uint_as_float(u0 << 16)
                  + w1 * __uint_as_float(u1 << 16);
            acc1 += w0 * __uint_as_float(u0 & 0xffff0000u)
                  + w1 * __uint_as_float(u1 & 0xffff0000u);
        }
        if (j < cnt) {
            const int s0 = __shfl(sv, j);
            const unsigned int u0 = *(const unsigned int*)&h[(long long)s0 * 128 + lane * 2];
            float e0 = el[(long long)s0 * 8 + hd] + erd;
            e0 = e0 >= 0.f ? e0 : NEG_SLOPE * e0;
            const float w0 = __expf(e0);
            den += w0;
            acc0 += w0 * __uint_as_float(u0 << 16);
            acc1 += w0 * __uint_as_float(u0 & 0xffff0000u);
        }
    }
    ushort2 o;
    if (end > start) {
        const float inv = 1.f / den;
        o.x = f2bf(acc0 * inv);
        o.y = f2bf(acc1 * inv);
    } else {
        o.x = 0; o.y = 0;
    }
    *(ushort2*)&rst[(long long)d * 128 + lane * 2] = o;
}

// ---------------------------------------------------------------------------
// K4: GCNII combine via bf16 MFMA, fully folded: out = acc + bvec + input.
// A-fragments (8 chunks) in registers (rst bf16 direct, h0 cvt), loaded
// once. B double-buffered in LDS, one barrier per BK=32 phase. FUSED
// GraphNorm stats in the epilogue (round-12 structure, session best).
// ---------------------------------------------------------------------------
__global__ __launch_bounds__(256) void combine_gemm_kernel(
    const unsigned short* __restrict__ rst, const float* __restrict__ h0,
    const float* __restrict__ input, const unsigned short* __restrict__ Wt,
    const float* __restrict__ bvec, const int* __restrict__ cums, int nb,
    float* __restrict__ sums, float* __restrict__ sumsq,
    float* __restrict__ x, int n)
{
    __shared__ unsigned short Bs[2][128][36];
    __shared__ float s_sum[128], s_sq[128];
    const int tid = threadIdx.x;
    const int wave = tid >> 6;
    const int lane = tid & 63;
    const int m16 = lane & 15;
    const int kg = lane >> 4;
    const int rowBase = blockIdx.x * 64;

    if (tid < 128) { s_sum[tid] = 0.f; s_sq[tid] = 0.f; }

    // A in registers: 8 chunks (rst 0-3 direct bf16, h0 4-7 cvt).
    int arow = rowBase + wave * 16 + m16;
    if (arow >= n) arow = n - 1;
    const long long aoff = (long long)arow * 128;
    bf16x8 af[8];
#pragma unroll
    for (int ci = 0; ci < 4; ++ci)
        af[ci] = *(const bf16x8*)&rst[aoff + ci * 32 + kg * 8];
#pragma unroll
    for (int ci = 0; ci < 4; ++ci) {
        const float4 v0 = *(const float4*)&h0[aoff + ci * 32 + kg * 8];
        const float4 v1 = *(const float4*)&h0[aoff + ci * 32 + kg * 8 + 4];
        bf16x8 pk;
        pk[0] = (short)f2bf(v0.x); pk[1] = (short)f2bf(v0.y);
        pk[2] = (short)f2bf(v0.z); pk[3] = (short)f2bf(v0.w);
        pk[4] = (short)f2bf(v1.x); pk[5] = (short)f2bf(v1.y);
        pk[6] = (short)f2bf(v1.z); pk[7] = (short)f2bf(v1.w);
        af[4 + ci] = pk;
    }

    const int rB = tid >> 1;
    const int p0 = (tid & 1) * 2;
    bf16x8 vb0, vb1;

    f32x4 acc[8];
#pragma unroll
    for (int t = 0; t < 8; ++t) acc[t] = (f32x4){0.f, 0.f, 0.f, 0.f};

    vb0 = *(const bf16x8*)&Wt[rB * 256 + p0 * 8];
    vb1 = *(const bf16x8*)&Wt[rB * 256 + p0 * 8 + 8];
    *(bf16x8*)&Bs[0][rB][p0 * 8] = vb0;
    *(bf16x8*)&Bs[0][rB][p0 * 8 + 8] = vb1;
    __syncthreads();

#pragma unroll
    for (int ci = 0; ci < 8; ++ci) {
        const int cur = ci & 1;
        if (ci < 7) {
            vb0 = *(const bf16x8*)&Wt[rB * 256 + (ci + 1) * 32 + p0 * 8];
            vb1 = *(const bf16x8*)&Wt[rB * 256 + (ci + 1) * 32 + p0 * 8 + 8];
        }
#pragma unroll
        for (int t = 0; t < 8; ++t) {
            const bf16x8 bfrag = *(const bf16x8*)&Bs[cur][t * 16 + m16][kg * 8];
            acc[t] = __builtin_amdgcn_mfma_f32_16x16x32_bf16(af[ci], bfrag, acc[t], 0, 0, 0);
        }
        if (ci < 7) {
            *(bf16x8*)&Bs[cur ^ 1][rB][p0 * 8] = vb0;
            *(bf16x8*)&Bs[cur ^ 1][rB][p0 * 8 + 8] = vb1;
            __syncthreads();
        }
    }

    // ---- epilogue: out = acc + bvec + input, fused GraphNorm partials ----
    int lo = 0, hi = nb;
    while (hi - lo > 1) {
        const int mid = (lo + hi) >> 1;
        if (cums[mid] <= rowBase) lo = mid; else hi = mid;
    }
    const int sid0 = lo;
    const int bnd = cums[sid0 + 1];

    const int r0 = rowBase + wave * 16 + kg * 4;
#pragma unroll
    for (int t = 0; t < 8; ++t) {
        const int col = t * 16 + m16;
        const float bv = bvec[col];
        float s0 = 0.f, q0 = 0.f, s1 = 0.f, q1 = 0.f;
#pragma unroll
        for (int j = 0; j < 4; ++j) {
            const int row = r0 + j;
            if (row < n) {
                const long long off = (long long)row * 128 + col;
                const float val = acc[t][j] + bv + input[off];
                x[off] = val;
                if (row < bnd) { s0 += val; q0 += val * val; }
                else           { s1 += val; q1 += val * val; }
            }
        }
        s0 += __shfl_xor(s0, 16, 64); s0 += __shfl_xor(s0, 32, 64);
        q0 += __shfl_xor(q0, 16, 64); q0 += __shfl_xor(q0, 32, 64);
        s1 += __shfl_xor(s1, 16, 64); s1 += __shfl_xor(s1, 32, 64);
        q1 += __shfl_xor(q1, 16, 64); q1 += __shfl_xor(q1, 32, 64);
        if (kg == 0) {
            atomicAdd(&s_sum[col], s0);
            atomicAdd(&s_sq[col], q0);
            if (s1 != 0.f || q1 != 0.f) {
                atomicAdd(&sums[(sid0 + 1) * 128 + col], s1);
                atomicAdd(&sumsq[(sid0 + 1) * 128 + col], q1);
            }
        }
    }
    __syncthreads();
    if (tid < 128) {
        atomicAdd(&sums[sid0 * 128 + tid], s_sum[tid]);
        atomicAdd(&sumsq[sid0 * 128 + tid], s_sq[tid]);
    }
}

// K6: sums -> mean, sumsq -> 1/(std+eps)  (unbiased, n-1)
__global__ __launch_bounds__(128) void finalize_stats_kernel(
    const int* __restrict__ cums, float* __restrict__ sums,
    float* __restrict__ sumsq)
{
    const int b = blockIdx.x;
    const int tid = threadIdx.x;
    const float cnt = (float)(cums[b + 1] - cums[b]);
    const float s = sums[b * 128 + tid];
    const float s2 = sumsq[b * 128 + tid];
    const float mean = s / cnt;
    float var = (s2 - s * mean) / (cnt - 1.f);
    var = fmaxf(var, 0.f);
    sums[b * 128 + tid] = mean;
    sumsq[b * 128 + tid] = 1.f / (sqrtf(var) + 1e-5f);
}

__global__ __launch_bounds__(256) void norm_kernel(
    const float* __restrict__ x, const float* __restrict__ mean,
    const float* __restrict__ istd, const int* __restrict__ cums, int nb,
    const float* __restrict__ gamma, const float* __restrict__ beta,
    float* __restrict__ out, int n)
{
    const long long gid = (long long)blockIdx.x * 256 + threadIdx.x;
    const int node = (int)(gid >> 5);
    if (node >= n) return;
    const int f4 = (int)(gid & 31);
    int lo = 0, hi = nb;
    while (hi - lo > 1) {
        const int mid = (lo + hi) >> 1;
        if (cums[mid] <= node) lo = mid; else hi = mid;
    }
    const float4 m = *(const float4*)&mean[lo * 128 + f4 * 4];
    const float4 is = *(const float4*)&istd[lo * 128 + f4 * 4];
    const float4 g = *(const float4*)&gamma[f4 * 4];
    const float4 bt = *(const float4*)&beta[f4 * 4];
    const float4 v = *(const float4*)&x[(long long)node * 128 + f4 * 4];
    float4 o;
    o.x = g.x * ((v.x - m.x) * is.x) + bt.x;
    o.y = g.y * ((v.y - m.y) * is.y) + bt.y;
    o.z = g.z * ((v.z - m.z) * is.z) + bt.z;
    o.w = g.w * ((v.w - m.w) * is.w) + bt.w;
    *(float4*)&out[(long long)node * 128 + f4 * 4] = o;
}

// ---------------------------------------------------------------------------
extern "C" void kernel_launch(void* const* d_in, const int* in_sizes, int n_in,
                              void* d_out, int out_size, void* d_ws, size_t ws_size,
                              hipStream_t stream) {
    const float* input   = (const float*)d_in[0];
    const float* h0      = (const float*)d_in[1];
    const int*   src     = (const int*)d_in[2];
    const int*   dst     = (const int*)d_in[3];
    const int*   cums    = (const int*)d_in[4];
    const int*   l_p     = (const int*)d_in[5];
    const float* lamda_p = (const float*)d_in[6];
    const float* alpha_p = (const float*)d_in[7];
    const float* W_fc    = (const float*)d_in[8];
    const float* attn_l  = (const float*)d_in[9];
    const float* attn_r  = (const float*)d_in[10];
    const float* gat_bias= (const float*)d_in[11];
    const float* W_comb  = (const float*)d_in[12];
    const float* gamma   = (const float*)d_in[13];
    const float* beta    = (const float*)d_in[14];

    const int n  = in_sizes[0] / 128;
    const int E  = in_sizes[2];
    const int nb = in_sizes[4] - 1;
    float* out = (float*)d_out;

    // workspace layout (all offsets 16B-aligned; sums/sumsq/deg contiguous)
    char* ws = (char*)d_ws;
    size_t o = 0;
#define ALLOC(ptr, type, count)                                              \
    type* ptr = (type*)(ws + o); o = (o + (size_t)(count) * sizeof(type) + 15) & ~(size_t)15;
    ALLOC(h,        unsigned short, (size_t)n * 128)
    ALLOC(el,       float,          (size_t)n * 8)
    ALLOC(er,       float,          (size_t)n * 8)
    ALLOC(rst,      unsigned short, (size_t)n * 128)
    ALLOC(sums,     float,          (size_t)nb * 128)
    ALLOC(sumsq,    float,          (size_t)nb * 128)
    ALLOC(deg,      int,            (size_t)n)
    ALLOC(row_ptr,  int,            (size_t)n + 1)
    ALLOC(cursor,   int,            (size_t)n)
    ALLOC(blockSums,int,            128)
    ALLOC(srcs,     int,            (size_t)E)
    ALLOC(Wt_fc,    unsigned short, 144 * 128)
    ALLOC(Wt_cb,    unsigned short, 128 * 256)
    ALLOC(bvec,     float,          128)
#undef ALLOC

    // single memset covering sums + sumsq + deg (contiguous)
    hipMemsetAsync(sums, 0, (char*)(deg + n) - (char*)sums, stream);

    // --- prep (weights -> bf16 transposed; attn columns + GCNII/bias fold) ---
    prep_kernel<<<64, 256, 0, stream>>>(
        W_fc, attn_l, attn_r, W_comb, gat_bias, l_p, lamda_p, alpha_p,
        Wt_fc, Wt_cb, bvec);

    // --- CSR build ---
    hist_kernel<<<(E + 255) / 256, 256, 0, stream>>>(dst, deg, E);
    const int nblk1 = (n + 1023) / 1024;
    scan1_kernel<<<nblk1, 256, 0, stream>>>(deg, row_ptr, blockSums, n);
    scan2_kernel<<<1, 128, 0, stream>>>(blockSums, nblk1);
    scan3_kernel<<<(n + 255) / 256, 256, 0, stream>>>(row_ptr, cursor, blockSums, n, E);
    scatter_kernel<<<(E + 255) / 256, 256, 0, stream>>>(src, dst, cursor, srcs, E);

    // --- dense pipeline ---
    const int gemm_grid = (n + 63) / 64;
    fc_gemm_kernel<<<gemm_grid, 256, 0, stream>>>(input, Wt_fc, h, el, er, n);

    aggregate_kernel<<<(n + 3) / 4, 256, 0, stream>>>(
        el, er, h, row_ptr, srcs, rst, n);

    combine_gemm_kernel<<<gemm_grid, 256, 0, stream>>>(
        rst, h0, input, Wt_cb, bvec, cums, nb, sums, sumsq, out, n);

    finalize_stats_kernel<<<nb, 128, 0, stream>>>(cums, sums, sumsq);

    const long long norm_threads = (long long)n * 32;
    norm_kernel<<<(int)((norm_threads + 255) / 256), 256, 0, stream>>>(
        out, sums, sumsq, cums, nb, gamma, beta, out, n);
}